// Round 2
// baseline (468.113 us; speedup 1.0000x reference)
//
#include <hip/hip_runtime.h>

#define SEQ 4096
#define DMODEL 1024
#define DSTATE 64
#define DINNER 2048
#define MROWS 8192            // BATCH*SEQ
#define NCAT 1152             // 1024 (dt) + 64 (xp) + 64 pad
#define NCHUNK 64             // scan chunks
#define LCHUNK 64             // steps per chunk

typedef __attribute__((ext_vector_type(8))) __bf16 bf16x8;
typedef __attribute__((ext_vector_type(8))) short short8;
typedef __attribute__((ext_vector_type(4))) float floatx4;

__device__ inline float bf2f(short s) {
  union { unsigned u; float f; } c;
  c.u = ((unsigned)(unsigned short)s) << 16;
  return c.f;
}
__device__ inline short f2bf(float f) {
  union { float f; unsigned u; } c; c.f = f;
  unsigned r = 0x7fffu + ((c.u >> 16) & 1u);
  return (short)((c.u + r) >> 16);
}
__device__ inline float silu_f(float v) { return v / (1.f + __expf(-v)); }
__device__ inline float softplus_f(float v) {
  return fmaxf(v, 0.f) + log1pf(__expf(-fabsf(v)));
}
// async global->LDS, 16B per lane. LDS dest = wave-uniform base + lane*16.
__device__ inline void gld_lds16(const void* g, void* l) {
  __builtin_amdgcn_global_load_lds(
      (__attribute__((address_space(1))) void*)g,
      (__attribute__((address_space(3))) void*)l, 16, 0, 0);
}

// ---------------- pre-pass: convert / transpose weights to bf16 [N,K] -------
__global__ void cvt_x_kernel(const float* __restrict__ x, short* __restrict__ xb, int n4) {
  int i = blockIdx.x * blockDim.x + threadIdx.x;
  if (i < n4) {
    float4 v = ((const float4*)x)[i];
    short4 o;
    o.x = f2bf(v.x); o.y = f2bf(v.y); o.z = f2bf(v.z); o.w = f2bf(v.w);
    ((short4*)xb)[i] = o;
  }
}

// in: fp32 [R,C] row-major -> out: bf16 [C,R] row-major (out stride = R)
__global__ void transpose_cvt(const float* __restrict__ in, short* __restrict__ out,
                              int R, int C) {
  __shared__ float tile[32][33];
  const int tx = threadIdx.x & 31, ty = threadIdx.x >> 5;   // 32 x 8
  const int cb = blockIdx.x * 32, rb = blockIdx.y * 32;
#pragma unroll
  for (int i = 0; i < 32; i += 8) {
    int r = rb + ty + i, c = cb + tx;
    tile[ty + i][tx] = (r < R && c < C) ? in[(size_t)r * C + c] : 0.f;
  }
  __syncthreads();
#pragma unroll
  for (int i = 0; i < 32; i += 8) {
    int orow = cb + ty + i, oc = rb + tx;   // out[c][r] = in[r][c]
    if (orow < C && oc < R) out[(size_t)orow * R + oc] = f2bf(tile[tx][ty + i]);
  }
}

// ---------------- m97-style bf16 GEMM, C = A[M,K] * Bt[N,K]^T ----------------
// MODE 0: in_proj epilogue -> xi=silu(col<2048), g=silu(col>=2048), both bf16
// MODE 1: dt/xp epilogue   -> col<1024: softplus+rowsum->md_sum (atomic)
//                             1024<=col<1088: bx fp32;  col>=1088: pad, drop
// MODE 2: out_proj epilogue-> out = v + b_out[col] + x[r,col]*D[col]  (fp32)
template <int MODE>
__global__ __launch_bounds__(256) void gemm_bt(
    const short* __restrict__ A, const short* __restrict__ Bt,
    const float* __restrict__ bias, const float* __restrict__ bias2,
    void* __restrict__ out0, void* __restrict__ out1,
    const float* __restrict__ xres, const float* __restrict__ Dvec,
    float* __restrict__ md_sum, int M, int N, int K)
{
  __shared__ __attribute__((aligned(16))) short sA[128 * 32];
  __shared__ __attribute__((aligned(16))) short sB[128 * 32];
  __shared__ float rowpart[128][2];

  const int tid = threadIdx.x;
  const int lane = tid & 63;
  const int w = tid >> 6;          // wave 0..3
  const int wr = w >> 1, wc = w & 1;
  const int m = lane & 15, quad = lane >> 4;
  const int bM = blockIdx.y * 128, bN = blockIdx.x * 128;

  floatx4 acc[4][4] = {};

  // staging: granule g -> LDS byte off g*16 == row(g/4)*64 + (g%4)*16
  const int g0 = (w * 2 + 0) * 64 + lane;
  const int g1 = (w * 2 + 1) * 64 + lane;
  const int r0 = g0 >> 2, c0 = g0 & 3;
  const int r1 = g1 >> 2, c1 = g1 & 3;
  const short* A0 = A + (size_t)(bM + r0) * K + c0 * 8;
  const short* A1 = A + (size_t)(bM + r1) * K + c1 * 8;
  const short* B0 = Bt + (size_t)(bN + r0) * K + c0 * 8;
  const short* B1 = Bt + (size_t)(bN + r1) * K + c1 * 8;
  short* dA0 = sA + (w * 2 + 0) * 512;  // 512 shorts = 1024B per wave-call
  short* dA1 = sA + (w * 2 + 1) * 512;
  short* dB0 = sB + (w * 2 + 0) * 512;
  short* dB1 = sB + (w * 2 + 1) * 512;

  for (int k0 = 0; k0 < K; k0 += 32) {
    __syncthreads();
    gld_lds16(A0 + k0, dA0);
    gld_lds16(A1 + k0, dA1);
    gld_lds16(B0 + k0, dB0);
    gld_lds16(B1 + k0, dB1);
    __syncthreads();   // drains vmcnt incl. global_load_lds
    bf16x8 af[4], bf[4];
#pragma unroll
    for (int rt = 0; rt < 4; ++rt)
      af[rt] = *(const bf16x8*)(sA + (wr * 64 + rt * 16 + m) * 32 + quad * 8);
#pragma unroll
    for (int ct = 0; ct < 4; ++ct)
      bf[ct] = *(const bf16x8*)(sB + (wc * 64 + ct * 16 + m) * 32 + quad * 8);
#pragma unroll
    for (int rt = 0; rt < 4; ++rt)
#pragma unroll
      for (int ct = 0; ct < 4; ++ct)
        acc[rt][ct] = __builtin_amdgcn_mfma_f32_16x16x32_bf16(af[rt], bf[ct], acc[rt][ct], 0, 0, 0);
  }

  const int rowbase = bM + wr * 64;
  const int colbase = bN + wc * 64;

  if (MODE == 0) {
    short* xi = (short*)out0;
    short* gg = (short*)out1;
#pragma unroll
    for (int rt = 0; rt < 4; ++rt)
#pragma unroll
      for (int ct = 0; ct < 4; ++ct) {
        const int col = colbase + ct * 16 + m;
#pragma unroll
        for (int reg = 0; reg < 4; ++reg) {
          const int r = rowbase + rt * 16 + quad * 4 + reg;
          float val = acc[rt][ct][reg] + bias[col];
          short h = f2bf(silu_f(val));
          if (col < DINNER) xi[(size_t)r * DINNER + col] = h;
          else              gg[(size_t)r * DINNER + (col - DINNER)] = h;
        }
      }
  } else if (MODE == 1) {
    float* bx = (float*)out0;
    float rsum[4][4];
#pragma unroll
    for (int rt = 0; rt < 4; ++rt)
#pragma unroll
      for (int reg = 0; reg < 4; ++reg) rsum[rt][reg] = 0.f;
#pragma unroll
    for (int rt = 0; rt < 4; ++rt)
#pragma unroll
      for (int ct = 0; ct < 4; ++ct) {
        const int col = colbase + ct * 16 + m;
#pragma unroll
        for (int reg = 0; reg < 4; ++reg) {
          float val = acc[rt][ct][reg];
          if (col < 1024) {
            rsum[rt][reg] += softplus_f(val + bias[col]);
          } else if (col < 1088) {
            const int r = rowbase + rt * 16 + quad * 4 + reg;
            bx[(size_t)r * DSTATE + (col - 1024)] = val + bias2[col - 1024];
          }
        }
      }
    if (bN < 1024) {   // block-uniform: only dt column-blocks reduce
#pragma unroll
      for (int rt = 0; rt < 4; ++rt)
#pragma unroll
        for (int reg = 0; reg < 4; ++reg) {
          float v = rsum[rt][reg];
          v += __shfl_xor(v, 1); v += __shfl_xor(v, 2);
          v += __shfl_xor(v, 4); v += __shfl_xor(v, 8);
          if (m == 0) rowpart[wr * 64 + rt * 16 + quad * 4 + reg][wc] = v;
        }
      __syncthreads();
      if (tid < 128)
        atomicAdd(&md_sum[bM + tid], rowpart[tid][0] + rowpart[tid][1]);
    }
  } else {
    float* out = (float*)out0;
#pragma unroll
    for (int rt = 0; rt < 4; ++rt)
#pragma unroll
      for (int ct = 0; ct < 4; ++ct) {
        const int col = colbase + ct * 16 + m;
#pragma unroll
        for (int reg = 0; reg < 4; ++reg) {
          const int r = rowbase + rt * 16 + quad * 4 + reg;
          out[(size_t)r * DMODEL + col] =
              acc[rt][ct][reg] + bias[col] + xres[(size_t)r * DMODEL + col] * Dvec[col];
        }
      }
  }
}

// ---------------- chunked selective scan (3 phases) --------------------------
__global__ void scan_phase1(const float* __restrict__ md_sum, const float* __restrict__ A_log,
                            const float* __restrict__ bx, float* __restrict__ a_buf,
                            float* __restrict__ chunk_prod, float* __restrict__ chunk_end) {
  const int n = threadIdx.x;                // 0..63 (state dim)
  const int c = blockIdx.x & (NCHUNK - 1);  // chunk
  const int b = blockIdx.x >> 6;            // batch
  const float An = -__expf(A_log[n]);
  float prod = 1.f, st = 0.f;
  const int t0 = c * LCHUNK;
  for (int i = 0; i < LCHUNK; ++i) {
    const int t = t0 + i;
    const float md = md_sum[b * SEQ + t] * (1.f / DMODEL);
    const float a = __expf(An * md);
    const size_t idx = ((size_t)(b * SEQ + t)) * DSTATE + n;
    st = a * st + bx[idx];
    prod *= a;
    a_buf[idx] = a;
  }
  chunk_prod[(b * NCHUNK + c) * DSTATE + n] = prod;
  chunk_end [(b * NCHUNK + c) * DSTATE + n] = st;
}

__global__ void scan_phase2(const float* __restrict__ chunk_prod,
                            const float* __restrict__ chunk_end,
                            float* __restrict__ chunk_init) {
  const int i = threadIdx.x;   // 0..127 = b*64 + n
  const int b = i >> 6, n = i & 63;
  float st = 0.f;
  for (int c = 0; c < NCHUNK; ++c) {
    const size_t idx = ((size_t)(b * NCHUNK + c)) * DSTATE + n;
    chunk_init[idx] = st;
    st = chunk_prod[idx] * st + chunk_end[idx];
  }
}

__global__ void scan_phase3(const float* __restrict__ a_buf, const float* __restrict__ bx,
                            const float* __restrict__ chunk_init, float* __restrict__ s_sum) {
  const int n = threadIdx.x;
  const int c = blockIdx.x & (NCHUNK - 1);
  const int b = blockIdx.x >> 6;
  float st = chunk_init[((size_t)(b * NCHUNK + c)) * DSTATE + n];
  const int t0 = c * LCHUNK;
  for (int i = 0; i < LCHUNK; ++i) {
    const int t = t0 + i;
    const size_t idx = ((size_t)(b * SEQ + t)) * DSTATE + n;
    st = a_buf[idx] * st + bx[idx];
    float v = st;
    v += __shfl_xor(v, 32); v += __shfl_xor(v, 16); v += __shfl_xor(v, 8);
    v += __shfl_xor(v, 4);  v += __shfl_xor(v, 2);  v += __shfl_xor(v, 1);
    if (n == 0) s_sum[b * SEQ + t] = v;
  }
}

// ---------------- y = s_sum * xi * g  (bf16 out) ------------------------------
__global__ void ymul_kernel(const short* __restrict__ xi, const short* __restrict__ g,
                            const float* __restrict__ s_sum, short* __restrict__ y) {
  const int row = blockIdx.x;
  const size_t base = (size_t)row * DINNER + threadIdx.x * 8;
  const float s = s_sum[row];
  short8 xv = *(const short8*)(xi + base);
  short8 gv = *(const short8*)(g + base);
  short8 yv;
#pragma unroll
  for (int k = 0; k < 8; ++k) yv[k] = f2bf(s * bf2f(xv[k]) * bf2f(gv[k]));
  *(short8*)(y + base) = yv;
}

// ---------------- launch ------------------------------------------------------
extern "C" void kernel_launch(void* const* d_in, const int* in_sizes, int n_in,
                              void* d_out, int out_size, void* d_ws, size_t ws_size,
                              hipStream_t stream) {
  const float* x     = (const float*)d_in[0];
  const float* W_in  = (const float*)d_in[1];
  const float* b_in  = (const float*)d_in[2];
  const float* W_xp  = (const float*)d_in[3];
  const float* b_xp  = (const float*)d_in[4];
  const float* W_dt  = (const float*)d_in[5];
  const float* b_dt  = (const float*)d_in[6];
  const float* W_out = (const float*)d_in[7];
  const float* b_out = (const float*)d_in[8];
  const float* A_log = (const float*)d_in[9];
  const float* Dv    = (const float*)d_in[10];

  char* ws = (char*)d_ws;
  size_t off = 0;
  auto alloc = [&](size_t bytes) -> void* {
    void* p = (void*)(ws + off);
    off += (bytes + 255) & ~(size_t)255;
    return p;
  };
  short* x_bf    = (short*)alloc((size_t)MROWS * DMODEL * 2);
  short* Wt_in   = (short*)alloc((size_t)4096 * 1024 * 2);
  short* Bcat    = (short*)alloc((size_t)NCAT * DINNER * 2);
  short* Wt_out  = (short*)alloc((size_t)1024 * 2048 * 2);
  short* xi      = (short*)alloc((size_t)MROWS * DINNER * 2);
  short* gbuf    = (short*)alloc((size_t)MROWS * DINNER * 2);
  short* ybuf    = (short*)alloc((size_t)MROWS * DINNER * 2);
  float* md_sum  = (float*)alloc((size_t)MROWS * 4);
  float* bx      = (float*)alloc((size_t)MROWS * DSTATE * 4);
  float* a_buf   = (float*)alloc((size_t)MROWS * DSTATE * 4);
  float* cprod   = (float*)alloc((size_t)2 * NCHUNK * DSTATE * 4);
  float* cend    = (float*)alloc((size_t)2 * NCHUNK * DSTATE * 4);
  float* cinit   = (float*)alloc((size_t)2 * NCHUNK * DSTATE * 4);
  float* s_sum   = (float*)alloc((size_t)MROWS * 4);

  // pre-pass: bf16 conversions + weight transposes
  cvt_x_kernel<<<(MROWS * DMODEL / 4 + 255) / 256, 256, 0, stream>>>(x, x_bf, MROWS * DMODEL / 4);
  transpose_cvt<<<dim3(4096 / 32, 1024 / 32), 256, 0, stream>>>(W_in, Wt_in, 1024, 4096);
  transpose_cvt<<<dim3(1024 / 32, 2048 / 32), 256, 0, stream>>>(W_dt, Bcat, 2048, 1024);
  transpose_cvt<<<dim3(64 / 32, 2048 / 32), 256, 0, stream>>>(W_xp, Bcat + (size_t)1024 * DINNER, 2048, 64);
  transpose_cvt<<<dim3(1024 / 32, 2048 / 32), 256, 0, stream>>>(W_out, Wt_out, 2048, 1024);  // FIX: was missing
  hipMemsetAsync(Bcat + (size_t)1088 * DINNER, 0, (size_t)64 * DINNER * 2, stream);  // pad rows
  hipMemsetAsync(md_sum, 0, (size_t)MROWS * 4, stream);

  // GEMM1: in_proj + silu split
  gemm_bt<0><<<dim3(4096 / 128, MROWS / 128), 256, 0, stream>>>(
      x_bf, Wt_in, b_in, nullptr, xi, gbuf, nullptr, nullptr, nullptr, MROWS, 4096, 1024);
  // GEMM2: dt (softplus rowsum) + xp (bx)
  gemm_bt<1><<<dim3(NCAT / 128, MROWS / 128), 256, 0, stream>>>(
      xi, Bcat, b_dt, b_xp, bx, nullptr, nullptr, nullptr, md_sum, MROWS, NCAT, 2048);
  // selective scan
  scan_phase1<<<2 * NCHUNK, DSTATE, 0, stream>>>(md_sum, A_log, bx, a_buf, cprod, cend);
  scan_phase2<<<1, 128, 0, stream>>>(cprod, cend, cinit);
  scan_phase3<<<2 * NCHUNK, DSTATE, 0, stream>>>(a_buf, bx, cinit, s_sum);
  // y = s_sum * xi * g
  ymul_kernel<<<MROWS, 256, 0, stream>>>(xi, gbuf, s_sum, ybuf);
  // GEMM4: out_proj + b_out + x*D
  gemm_bt<2><<<dim3(1024 / 128, MROWS / 128), 256, 0, stream>>>(
      ybuf, Wt_out, b_out, nullptr, d_out, nullptr, x, Dv, nullptr, MROWS, 1024, 2048);
}